// Round 8
// baseline (3701.363 us; speedup 1.0000x reference)
//
#include <hip/hip_runtime.h>

typedef __attribute__((ext_vector_type(8))) __bf16 bf16x8;
typedef __attribute__((ext_vector_type(4))) float f32x4;
typedef unsigned short u16;

#define BB 64
#define NPIX 1024
#define NELEM (BB*64*NPIX)           // 4194304

// LDS input layout: [plane hi/lo][pixel 6*34][chunk-slot swizzled 8x8 u16]
#define PLANE (6*34*64)              // 13056 u16 per plane

__device__ __forceinline__ int swz8(int c8, int p) {
    return (c8 + ((p + (p >> 2)) & 7)) & 7;
}

__device__ __forceinline__ u16 bf16_rn(float x) {
    unsigned u = __float_as_uint(x);
    unsigned r = u + 0x7FFFu + ((u >> 16) & 1u);
    return (u16)(r >> 16);
}
__device__ __forceinline__ float bf2f(u16 u) {
    return __uint_as_float(((unsigned)u) << 16);
}
__device__ __forceinline__ void split2(float x, u16& h, u16& l) {
    h = bf16_rn(x);
    float hf = __uint_as_float(((unsigned)h) << 16);
    l = bf16_rn(x - hf);
}

// ---------------------------------------------------------------------------
__global__ __launch_bounds__(256) void prep_w_k(
    const float* __restrict__ w, u16* __restrict__ wt)
{
    int t = blockIdx.x*256 + threadIdx.x;
    if (t >= 9216) return;
    int lane = t & 63;
    int f = t >> 6;
    int ty  = f & 1;
    int mt  = (f >> 1) & 3;
    int kc  = (f >> 3) & 1;
    int tap = f >> 4;
    int cout = mt*16 + (lane & 15);
    int quad = lane >> 4;
    u16 v[8];
#pragma unroll
    for (int j = 0; j < 8; ++j) {
        int cin = kc*32 + quad*8 + j;
        float x = w[((size_t)cout*65 + (cin+1))*9 + tap];
        u16 h, l; split2(x, h, l);
        v[j] = ty ? l : h;
    }
    u16* dst = wt + ((size_t)tap*8192 + (((kc*4+mt)*2+ty)*64 + lane)*8);
    *(ushort4*)(dst)     = make_ushort4(v[0], v[1], v[2], v[3]);
    *(ushort4*)(dst + 4) = make_ushort4(v[4], v[5], v[6], v[7]);
}

__global__ __launch_bounds__(256) void smap_k(
    const float* __restrict__ w, float* __restrict__ smap)
{
    int t = blockIdx.x*256 + threadIdx.x;
    int cout = t >> 10;
    int pix = t & 1023;
    int y = pix >> 5, x = pix & 31;
    float s = 0.f;
#pragma unroll
    for (int dy = 0; dy < 3; ++dy)
#pragma unroll
        for (int dx = 0; dx < 3; ++dx) {
            int yy = y + dy - 1, xx = x + dx - 1;
            if ((unsigned)yy < 32u && (unsigned)xx < 32u)
                s += w[(size_t)cout*65*9 + dy*3 + dx];
        }
    smap[t] = s;
}

// ---------------------------------------------------------------------------
// Fused conv3x3, kc-pipelined, batched staging loads.
//  mode 0: v = src0 (fp32, raw)
//  mode 1: v = src0 + fc[ch] + sum_{jj<nk} fa[jj][ch]*bf2f(k_jj)
//  mode 2: v = relu(ka[ch]*bf2f(srcb) + kb[ch])
// ---------------------------------------------------------------------------
__global__ __launch_bounds__(256, 2) void conv_mfma_k(
    const float* __restrict__ src0, const u16* __restrict__ srcb,
    const u16* __restrict__ kp0, const u16* __restrict__ kp1,
    const u16* __restrict__ kp2, const u16* __restrict__ kp3,
    const u16* __restrict__ kp4,
    float* __restrict__ part,
    const float* __restrict__ gns, const float* __restrict__ gnb,
    const float* __restrict__ gks, const float* __restrict__ gkb,
    const u16* __restrict__ wt, const float* __restrict__ smap,
    const float* __restrict__ bias, u16* __restrict__ out, float tval,
    int mode, int nk, int slot_in, int slot_out,
    float a1, float a2, float a3, float a4, float a5)
{
    __shared__ u16 lds_in[2*PLANE];          // 52224 B
    __shared__ float kaf[5][64];
    __shared__ float kbf[64];
    __shared__ float sgA[5][64];
    __shared__ float ps[256], pss[256];
    __shared__ float rg[64], rgq[64];

    const int rt  = blockIdx.x;
    const int b   = blockIdx.y;
    const int tid = threadIdx.x;
    const int wv   = tid >> 6;
    const int lane = tid & 63;
    const int quad = lane >> 4;
    const int n15  = lane & 15;

    // ---- prelude: per-channel affine coefficients ----
    if (mode == 2) {
        if (tid < 64) {
            int g = tid & 31, st = tid >> 5;
            const float* pp = part + ((((size_t)slot_in*64 + b)*32 + g)*8)*2 + st;
            sgA[0][st*32+g] = pp[0]+pp[2]+pp[4]+pp[6]+pp[8]+pp[10]+pp[12]+pp[14];
        }
        __syncthreads();
        if (tid < 64) {
            int g = tid >> 1;
            float mu   = sgA[0][g] * (1.f/2048.f);
            float var  = sgA[0][32+g] * (1.f/2048.f) - mu*mu;
            float rstd = rsqrtf(var + 1e-5f);
            float a = gns[tid]*rstd;
            kaf[0][tid] = a;
            kbf[tid] = gnb[tid] - mu*a;
        }
    } else if (mode == 1) {
        if (tid < 64) {
            int g = tid & 31, st = tid >> 5;
            for (int jj = 0; jj < nk; ++jj) {
                const float* pp = part + ((((size_t)(1+jj)*64 + b)*32 + g)*8)*2 + st;
                sgA[jj][st*32+g] = pp[0]+pp[2]+pp[4]+pp[6]+pp[8]+pp[10]+pp[12]+pp[14];
            }
        }
        __syncthreads();
        if (tid < 64) {
            const float aa[5] = {a1, a2, a3, a4, a5};
            int g = tid >> 1;
            float acb = 0.f;
            for (int jj = 0; jj < nk; ++jj) {
                float mu   = sgA[jj][g] * (1.f/2048.f);
                float var  = sgA[jj][32+g] * (1.f/2048.f) - mu*mu;
                float rstd = rsqrtf(var + 1e-5f);
                float a = gks[tid]*rstd;
                float c = gkb[tid] - mu*a;
                kaf[jj][tid] = aa[jj]*a;
                acb += aa[jj]*c;
            }
            kbf[tid] = acb;
        }
    } else {
        if (tid < 64) { kaf[0][tid] = 1.f; kbf[tid] = 0.f; }
    }
    __syncthreads();

    // ---- staging: batched loads (phase 1) then process (phase 2), per half
    float4  Ya[3], Yb[3];
    ushort4 Ka[3][5], Kb[3][5];

    auto load_half = [&](int hh) {
#pragma unroll
        for (int ii = 0; ii < 3; ++ii) {
            int u  = tid + (hh*3 + ii)*256;
            int q4 = u & 7;
            int t2 = u >> 3;
            int rr = t2 % 6;
            int c2 = t2 / 6;
            int gr = rt*4 + rr - 1;
            if ((unsigned)gr < 32u) {
                const size_t base = (((size_t)b*64 + c2*2)*32 + gr)*32 + q4*4;
                if (mode == 2) {
                    Ka[ii][0] = *(const ushort4*)(srcb + base);
                    Kb[ii][0] = *(const ushort4*)(srcb + base + 1024);
                } else {
                    Ya[ii] = *(const float4*)(src0 + base);
                    Yb[ii] = *(const float4*)(src0 + base + 1024);
                    if (mode == 1) {
                        const u16* kps[5] = {kp0, kp1, kp2, kp3, kp4};
#pragma unroll
                        for (int jj = 0; jj < 5; ++jj) {
                            if (jj >= nk) break;
                            Ka[ii][jj] = *(const ushort4*)(kps[jj] + base);
                            Kb[ii][jj] = *(const ushort4*)(kps[jj] + base + 1024);
                        }
                    }
                }
            }
        }
    };

    auto process_half = [&](int hh) {
#pragma unroll
        for (int ii = 0; ii < 3; ++ii) {
            int u  = tid + (hh*3 + ii)*256;
            int q4 = u & 7;
            int t2 = u >> 3;
            int rr = t2 % 6;
            int c2 = t2 / 6;
            int gr = rt*4 + rr - 1;
            bool ok = (unsigned)gr < 32u;
            int ch0 = c2*2, ch1 = ch0 + 1;
            float4 a0 = make_float4(0.f,0.f,0.f,0.f), a1v = a0;
            if (ok) {
                if (mode == 2) {
                    float A0 = kaf[0][ch0], B0 = kbf[ch0];
                    float A1 = kaf[0][ch1], B1 = kbf[ch1];
                    a0.x = fmaxf(fmaf(bf2f(Ka[ii][0].x),A0,B0), 0.f);
                    a0.y = fmaxf(fmaf(bf2f(Ka[ii][0].y),A0,B0), 0.f);
                    a0.z = fmaxf(fmaf(bf2f(Ka[ii][0].z),A0,B0), 0.f);
                    a0.w = fmaxf(fmaf(bf2f(Ka[ii][0].w),A0,B0), 0.f);
                    a1v.x = fmaxf(fmaf(bf2f(Kb[ii][0].x),A1,B1), 0.f);
                    a1v.y = fmaxf(fmaf(bf2f(Kb[ii][0].y),A1,B1), 0.f);
                    a1v.z = fmaxf(fmaf(bf2f(Kb[ii][0].z),A1,B1), 0.f);
                    a1v.w = fmaxf(fmaf(bf2f(Kb[ii][0].w),A1,B1), 0.f);
                } else {
                    a0 = Ya[ii]; a1v = Yb[ii];
                    if (mode == 1) {
                        float f0 = kbf[ch0], f1 = kbf[ch1];
                        a0.x += f0; a0.y += f0; a0.z += f0; a0.w += f0;
                        a1v.x += f1; a1v.y += f1; a1v.z += f1; a1v.w += f1;
#pragma unroll
                        for (int jj = 0; jj < 5; ++jj) {
                            if (jj >= nk) break;
                            float fa0 = kaf[jj][ch0], fa1 = kaf[jj][ch1];
                            a0.x = fmaf(fa0, bf2f(Ka[ii][jj].x), a0.x);
                            a0.y = fmaf(fa0, bf2f(Ka[ii][jj].y), a0.y);
                            a0.z = fmaf(fa0, bf2f(Ka[ii][jj].z), a0.z);
                            a0.w = fmaf(fa0, bf2f(Ka[ii][jj].w), a0.w);
                            a1v.x = fmaf(fa1, bf2f(Kb[ii][jj].x), a1v.x);
                            a1v.y = fmaf(fa1, bf2f(Kb[ii][jj].y), a1v.y);
                            a1v.z = fmaf(fa1, bf2f(Kb[ii][jj].z), a1v.z);
                            a1v.w = fmaf(fa1, bf2f(Kb[ii][jj].w), a1v.w);
                        }
                    }
                }
            }
            float v0[4] = {a0.x, a0.y, a0.z, a0.w};
            float v1[4] = {a1v.x, a1v.y, a1v.z, a1v.w};
            int c8 = c2 >> 2, cl = c2 & 3;
            int pbase = rr*34 + 1 + q4*4;
#pragma unroll
            for (int j = 0; j < 4; ++j) {
                int p = pbase + j;
                int au = p*64 + swz8(c8, p)*8 + cl*2;
                u16 h0,l0,h1,l1;
                split2(v0[j], h0, l0);
                split2(v1[j], h1, l1);
                *(unsigned*)&lds_in[au]         = (unsigned)h0 | ((unsigned)h1 << 16);
                *(unsigned*)&lds_in[au + PLANE] = (unsigned)l0 | ((unsigned)l1 << 16);
            }
        }
    };

    f32x4 acc[4][2] = {};

    auto do_mfma = [&](int kc) {
#pragma unroll
        for (int tap = 0; tap < 9; ++tap) {
            const int dy = tap / 3;
            const int dx = tap - dy*3;
            const int rowoff = (wv + dy)*34 + dx;
            const u16* wtap = wt + (size_t)tap*8192;
            bf16x8 A[4][2], Bf[2][2];
#pragma unroll
            for (int mt = 0; mt < 4; ++mt)
#pragma unroll
                for (int ty = 0; ty < 2; ++ty)
                    A[mt][ty] = *(const bf16x8*)
                        &wtap[(((kc*4+mt)*2+ty)*64 + lane)*8];
#pragma unroll
            for (int nt = 0; nt < 2; ++nt) {
                int p = rowoff + nt*16 + n15;
                int au = p*64 + swz8(kc*4 + quad, p)*8;
                Bf[nt][0] = *(const bf16x8*)&lds_in[au];
                Bf[nt][1] = *(const bf16x8*)&lds_in[au + PLANE];
            }
#pragma unroll
            for (int mt = 0; mt < 4; ++mt)
#pragma unroll
                for (int nt = 0; nt < 2; ++nt) {
                    acc[mt][nt] = __builtin_amdgcn_mfma_f32_16x16x32_bf16(
                        A[mt][0], Bf[nt][0], acc[mt][nt], 0, 0, 0);
                    acc[mt][nt] = __builtin_amdgcn_mfma_f32_16x16x32_bf16(
                        A[mt][0], Bf[nt][1], acc[mt][nt], 0, 0, 0);
                    acc[mt][nt] = __builtin_amdgcn_mfma_f32_16x16x32_bf16(
                        A[mt][1], Bf[nt][0], acc[mt][nt], 0, 0, 0);
                }
        }
    };

    // ---- pipeline: stage kc0 | mfma kc0 + stage kc1 | mfma kc1 ----
    load_half(0);
    process_half(0);
    load_half(1);
    // zero horizontal halo cols (both halves' slots)
#pragma unroll
    for (int i = 0; i < 3; ++i) {
        int u = tid + i*256;
        int c2 = u & 31;
        int t2 = u >> 5;
        int rr = t2 % 6;
        int z  = t2 / 6;
        int e  = z & 1, pl = z >> 1;
        int p  = rr*34 + e*33;
        int au = p*64 + swz8(c2 >> 2, p)*8 + (c2 & 3)*2 + pl*PLANE;
        *(unsigned*)&lds_in[au] = 0u;
    }
    __syncthreads();
    do_mfma(0);
    process_half(1);   // writes kc1 slots — disjoint from kc0 reads
    __syncthreads();
    do_mfma(1);

    // ---- epilogue: write bf16 out + per-block GN partials ----
    const int orow = rt*4 + wv;
#pragma unroll
    for (int mt = 0; mt < 4; ++mt) {
#pragma unroll
        for (int r = 0; r < 4; ++r) {
            int cout = mt*16 + quad*4 + r;
            float bs = bias[cout];
            const float* sp = smap + (size_t)cout*1024 + orow*32;
            u16* op = out + (((size_t)b*64 + cout)*32 + orow)*32;
            float v0 = acc[mt][0][r] + bs + tval*sp[n15];
            float v1 = acc[mt][1][r] + bs + tval*sp[16 + n15];
            op[n15]      = bf16_rn(v0);
            op[16 + n15] = bf16_rn(v1);
            float s = v0 + v1;
            float q = v0*v0 + v1*v1;
            s += __shfl_xor(s, 1); q += __shfl_xor(q, 1);
            s += __shfl_xor(s, 2); q += __shfl_xor(q, 2);
            s += __shfl_xor(s, 4); q += __shfl_xor(q, 4);
            s += __shfl_xor(s, 8); q += __shfl_xor(q, 8);
            if (n15 == 0) { ps[wv*64 + cout] = s; pss[wv*64 + cout] = q; }
        }
    }
    __syncthreads();
    if (tid < 64) {
        rg[tid]  = ps[tid]  + ps[64+tid]  + ps[128+tid]  + ps[192+tid];
        rgq[tid] = pss[tid] + pss[64+tid] + pss[128+tid] + pss[192+tid];
    }
    __syncthreads();
    if (tid < 32) {
        float S  = rg[2*tid]  + rg[2*tid+1];
        float SS = rgq[2*tid] + rgq[2*tid+1];
        float* pp = part + ((((size_t)slot_out*64 + b)*32 + tid)*8 + rt)*2;
        pp[0] = S; pp[1] = SS;
    }
}

// ---------------------------------------------------------------------------
// Per-step final combine (in-place): y += sum_j (B_j*dt) * gn2affine(k_j).
// ---------------------------------------------------------------------------
__global__ __launch_bounds__(256) void final_combine_k(
    float* __restrict__ y,
    const u16* __restrict__ k0, const u16* __restrict__ k1,
    const u16* __restrict__ k2, const u16* __restrict__ k3,
    const u16* __restrict__ k4, const u16* __restrict__ k5,
    const float* __restrict__ part,
    const float* __restrict__ g2s, const float* __restrict__ g2b,
    float b0, float b1, float b2, float b3, float b4, float b5)
{
    const int bidx = blockIdx.x;
    const int b = bidx >> 6, ch = bidx & 63, g = ch >> 1;
    const int t = threadIdx.x;
    __shared__ float rs[6][2];
    if (t < 12) {
        int jj = t >> 1, st = t & 1;
        const float* pp = part + ((((size_t)(1+jj)*64 + b)*32 + g)*8)*2 + st;
        rs[jj][st] = pp[0]+pp[2]+pp[4]+pp[6]+pp[8]+pp[10]+pp[12]+pp[14];
    }
    __syncthreads();
    const float bb[6] = {b0, b1, b2, b3, b4, b5};
    float fa[6], fcs = 0.f;
#pragma unroll
    for (int jj = 0; jj < 6; ++jj) {
        float mu   = rs[jj][0] * (1.f/2048.f);
        float var  = rs[jj][1] * (1.f/2048.f) - mu*mu;
        float rstd = rsqrtf(var + 1e-5f);
        float a = g2s[ch]*rstd;
        float c = g2b[ch] - mu*a;
        fa[jj] = bb[jj]*a;
        fcs   += bb[jj]*c;
    }
    const size_t base = ((size_t)bidx*256 + t)*4;
    float4 r = *(const float4*)(y + base);
    r.x += fcs; r.y += fcs; r.z += fcs; r.w += fcs;
    const u16* kp[6] = {k0, k1, k2, k3, k4, k5};
#pragma unroll
    for (int jj = 0; jj < 6; ++jj) {
        ushort4 kv = *(const ushort4*)(kp[jj] + base);
        r.x = fmaf(fa[jj], bf2f(kv.x), r.x);
        r.y = fmaf(fa[jj], bf2f(kv.y), r.y);
        r.z = fmaf(fa[jj], bf2f(kv.z), r.z);
        r.w = fmaf(fa[jj], bf2f(kv.w), r.w);
    }
    *(float4*)(y + base) = r;
}

// ---------------------------------------------------------------------------

static const double A_[5][5] = {
    {0.161, 0, 0, 0, 0},
    {-0.008480655492356989, 0.335480655492357, 0, 0, 0},
    {2.8971530571054935, -6.359448489975075, 4.3622954328695815, 0, 0},
    {5.325864828439257, -11.748883564062828, 7.4955393428898365, -0.09249506636175525, 0},
    {5.86145544294642, -12.92096931784711, 8.159367898576159, -0.071584973281401, -0.028269050394068383},
};
static const double B_[6] = {
    0.09646076681806523, 0.01, 0.4798896504144996,
    1.379008574103742, -3.290069515436081, 2.324710524099774,
};
static const double C_[5] = {0.161, 0.327, 0.9, 0.9800255409045097, 1.0};

extern "C" void kernel_launch(void* const* d_in, const int* in_sizes, int n_in,
                              void* d_out, int out_size, void* d_ws, size_t ws_size,
                              hipStream_t stream)
{
    const float* x   = (const float*)d_in[0];
    const float* c1w = (const float*)d_in[1];
    const float* c1b = (const float*)d_in[2];
    const float* g1s = (const float*)d_in[3];
    const float* g1b = (const float*)d_in[4];
    const float* c2w = (const float*)d_in[5];
    const float* c2b = (const float*)d_in[6];
    const float* g2s = (const float*)d_in[7];
    const float* g2b = (const float*)d_in[8];

    float* y  = (float*)d_out;
    u16*   wsb = (u16*)d_ws;
    u16*   h  = wsb;
    u16*   k[6];
    for (int i = 0; i < 6; ++i) k[i] = wsb + (size_t)(1 + i) * NELEM;
    u16*   wt1   = wsb + (size_t)7*NELEM;
    u16*   wt2   = wt1 + 73728;
    float* smap1 = (float*)(wt2 + 73728);
    float* smap2 = smap1 + 65536;
    float* part  = smap2 + 65536;    // 7*64*32*8*2 floats

    const double dt = 0.125;
    const float dtf = 0.125f;

    prep_w_k<<<36, 256, 0, stream>>>(c1w, wt1);
    prep_w_k<<<36, 256, 0, stream>>>(c2w, wt2);
    smap_k<<<256, 256, 0, stream>>>(c1w, smap1);
    smap_k<<<256, 256, 0, stream>>>(c2w, smap2);

    hipMemcpyAsync(y, x, (size_t)NELEM * sizeof(float),
                   hipMemcpyDeviceToDevice, stream);

    const dim3 cgrid(8, BB);

    for (int s = 0; s < 8; ++s) {
        const float t0 = dtf * (float)s;
        for (int j = 0; j < 6; ++j) {
            const float tj = (j == 0) ? t0 : t0 + (float)C_[j-1] * dtf;
            float a[5] = {0,0,0,0,0};
            for (int i = 0; i < j; ++i) a[i] = (float)(A_[j-1][i] * dt);
            // conv1: stage combine on read (mode 1; raw mode 0 at j==0),
            // GN1 stats -> slot 0; out = h (bf16)
            conv_mfma_k<<<cgrid, 256, 0, stream>>>(
                y, nullptr, k[0], k[1], k[2], k[3], k[4],
                part, g1s, g1b, g2s, g2b,
                wt1, smap1, c1b, h, tj,
                (j == 0) ? 0 : 1, j, 0, 0,
                a[0], a[1], a[2], a[3], a[4]);
            // conv2: GN1 affine+ReLU on bf16 read (slot 0), GN2 stats -> 1+j
            conv_mfma_k<<<cgrid, 256, 0, stream>>>(
                nullptr, h, nullptr, nullptr, nullptr, nullptr, nullptr,
                part, g1s, g1b, g2s, g2b,
                wt2, smap2, c2b, k[j], tj,
                2, 0, 0, 1 + j,
                0.f, 0.f, 0.f, 0.f, 0.f);
        }
        final_combine_k<<<4096, 256, 0, stream>>>(
            y, k[0], k[1], k[2], k[3], k[4], k[5], part, g2s, g2b,
            (float)(B_[0]*dt), (float)(B_[1]*dt), (float)(B_[2]*dt),
            (float)(B_[3]*dt), (float)(B_[4]*dt), (float)(B_[5]*dt));
    }
}

// Round 9
// 2897.708 us; speedup vs baseline: 1.2773x; 1.2773x over previous
//
#include <hip/hip_runtime.h>

typedef __attribute__((ext_vector_type(8))) __bf16 bf16x8;
typedef __attribute__((ext_vector_type(4))) float f32x4;
typedef unsigned short u16;

#define BB 64
#define NPIX 1024
#define NELEM (BB*64*NPIX)           // 4194304
#define NRT 16                       // row-tiles of 2 rows

// LDS input layout: [plane hi/lo][pixel 4*34][chunk-slot swizzled 8x8 u16]
#define PLANE (4*34*64)              // 8704 u16 per plane

__device__ __forceinline__ int swz8(int c8, int p) {
    return (c8 + ((p + (p >> 2)) & 7)) & 7;
}

__device__ __forceinline__ u16 bf16_rn(float x) {
    unsigned u = __float_as_uint(x);
    unsigned r = u + 0x7FFFu + ((u >> 16) & 1u);
    return (u16)(r >> 16);
}
__device__ __forceinline__ float bf2f(u16 u) {
    return __uint_as_float(((unsigned)u) << 16);
}
__device__ __forceinline__ void split2(float x, u16& h, u16& l) {
    h = bf16_rn(x);
    float hf = __uint_as_float(((unsigned)h) << 16);
    l = bf16_rn(x - hf);
}

// ---------------------------------------------------------------------------
__global__ __launch_bounds__(256) void prep_w_k(
    const float* __restrict__ w, u16* __restrict__ wt)
{
    int t = blockIdx.x*256 + threadIdx.x;
    if (t >= 9216) return;
    int lane = t & 63;
    int f = t >> 6;
    int ty  = f & 1;
    int mt  = (f >> 1) & 3;
    int kc  = (f >> 3) & 1;
    int tap = f >> 4;
    int cout = mt*16 + (lane & 15);
    int quad = lane >> 4;
    u16 v[8];
#pragma unroll
    for (int j = 0; j < 8; ++j) {
        int cin = kc*32 + quad*8 + j;
        float x = w[((size_t)cout*65 + (cin+1))*9 + tap];
        u16 h, l; split2(x, h, l);
        v[j] = ty ? l : h;
    }
    u16* dst = wt + ((size_t)tap*8192 + (((kc*4+mt)*2+ty)*64 + lane)*8);
    *(ushort4*)(dst)     = make_ushort4(v[0], v[1], v[2], v[3]);
    *(ushort4*)(dst + 4) = make_ushort4(v[4], v[5], v[6], v[7]);
}

__global__ __launch_bounds__(256) void smap_k(
    const float* __restrict__ w, float* __restrict__ smap)
{
    int t = blockIdx.x*256 + threadIdx.x;
    int cout = t >> 10;
    int pix = t & 1023;
    int y = pix >> 5, x = pix & 31;
    float s = 0.f;
#pragma unroll
    for (int dy = 0; dy < 3; ++dy)
#pragma unroll
        for (int dx = 0; dx < 3; ++dx) {
            int yy = y + dy - 1, xx = x + dx - 1;
            if ((unsigned)yy < 32u && (unsigned)xx < 32u)
                s += w[(size_t)cout*65*9 + dy*3 + dx];
        }
    smap[t] = s;
}

// ---------------------------------------------------------------------------
// Fused conv3x3 (bf16 hi/lo MFMA). 2-row tiles, 4 blocks/CU.
//  mode 0: v = src0 (fp32, raw)
//  mode 1: v = src0 + fc[ch] + sum_{jj<nk} fa[jj][ch]*bf2f(k_jj)
//  mode 2: v = relu(ka[ch]*bf2f(srcb) + kb[ch])
// Block tile: 64 cout x 2 rows x 32 px. Wave w: row (w&1), cout-half (w>>1).
// ---------------------------------------------------------------------------
__global__ __launch_bounds__(256, 4) void conv_mfma_k(
    const float* __restrict__ src0, const u16* __restrict__ srcb,
    const u16* __restrict__ kp0, const u16* __restrict__ kp1,
    const u16* __restrict__ kp2, const u16* __restrict__ kp3,
    const u16* __restrict__ kp4,
    float* __restrict__ part,
    const float* __restrict__ gns, const float* __restrict__ gnb,
    const float* __restrict__ gks, const float* __restrict__ gkb,
    const u16* __restrict__ wt, const float* __restrict__ smap,
    const float* __restrict__ bias, u16* __restrict__ out, float tval,
    int mode, int nk, int slot_in, int slot_out,
    float a1, float a2, float a3, float a4, float a5)
{
    __shared__ u16 lds_in[2*PLANE];          // 34816 B
    __shared__ float kaf[5][64];
    __shared__ float kbf[64];
    __shared__ float sgA[5][64];
    __shared__ float ps[128], pss[128];      // [row2][cout64]

    const int rt  = blockIdx.x;              // 0..15
    const int b   = blockIdx.y;
    const int tid = threadIdx.x;
    const int wv   = tid >> 6;
    const int lane = tid & 63;
    const int quad = lane >> 4;
    const int n15  = lane & 15;
    const int r0   = wv & 1;                 // row in tile
    const int mh   = wv >> 1;                // cout half

    // ---- prelude: per-channel affine coefficients ----
    if (mode == 2) {
        if (tid < 64) {
            int g = tid & 31, st = tid >> 5;
            const float* pp = part + ((((size_t)slot_in*64 + b)*32 + g)*NRT)*2 + st;
            float v = 0.f;
#pragma unroll
            for (int q = 0; q < NRT; ++q) v += pp[2*q];
            sgA[0][st*32+g] = v;
        }
        __syncthreads();
        if (tid < 64) {
            int g = tid >> 1;
            float mu   = sgA[0][g] * (1.f/2048.f);
            float var  = sgA[0][32+g] * (1.f/2048.f) - mu*mu;
            float rstd = rsqrtf(var + 1e-5f);
            float a = gns[tid]*rstd;
            kaf[0][tid] = a;
            kbf[tid] = gnb[tid] - mu*a;
        }
    } else if (mode == 1) {
        if (tid < 64) {
            int g = tid & 31, st = tid >> 5;
            for (int jj = 0; jj < nk; ++jj) {
                const float* pp = part + ((((size_t)(1+jj)*64 + b)*32 + g)*NRT)*2 + st;
                float v = 0.f;
#pragma unroll
                for (int q = 0; q < NRT; ++q) v += pp[2*q];
                sgA[jj][st*32+g] = v;
            }
        }
        __syncthreads();
        if (tid < 64) {
            const float aa[5] = {a1, a2, a3, a4, a5};
            int g = tid >> 1;
            float acb = 0.f;
            for (int jj = 0; jj < nk; ++jj) {
                float mu   = sgA[jj][g] * (1.f/2048.f);
                float var  = sgA[jj][32+g] * (1.f/2048.f) - mu*mu;
                float rstd = rsqrtf(var + 1e-5f);
                float a = gks[tid]*rstd;
                float c = gkb[tid] - mu*a;
                kaf[jj][tid] = aa[jj]*a;
                acb += aa[jj]*c;
            }
            kbf[tid] = acb;
        }
    } else {
        if (tid < 64) { kaf[0][tid] = 1.f; kbf[tid] = 0.f; }
    }
    __syncthreads();

    // ---- stage input: 32 ch-pairs x 4 rows x 8 col-quads (interleaved) ----
#pragma unroll
    for (int i = 0; i < 4; ++i) {
        int u  = tid + i*256;          // 0..1023
        int q4 = u & 7;
        int t2 = u >> 3;               // 0..127
        int rr = t2 & 3;
        int c2 = t2 >> 2;              // 0..31
        int gr = rt*2 + rr - 1;
        bool ok = (unsigned)gr < 32u;
        int ch0 = c2*2, ch1 = ch0 + 1;
        float4 a0 = make_float4(0.f,0.f,0.f,0.f), a1v = a0;
        if (ok) {
            const size_t base = (((size_t)b*64 + ch0)*32 + gr)*32 + q4*4;
            if (mode == 2) {
                ushort4 H0 = *(const ushort4*)(srcb + base);
                ushort4 H1 = *(const ushort4*)(srcb + base + 1024);
                float A0 = kaf[0][ch0], B0 = kbf[ch0];
                float A1 = kaf[0][ch1], B1 = kbf[ch1];
                a0.x = fmaxf(fmaf(bf2f(H0.x),A0,B0), 0.f);
                a0.y = fmaxf(fmaf(bf2f(H0.y),A0,B0), 0.f);
                a0.z = fmaxf(fmaf(bf2f(H0.z),A0,B0), 0.f);
                a0.w = fmaxf(fmaf(bf2f(H0.w),A0,B0), 0.f);
                a1v.x = fmaxf(fmaf(bf2f(H1.x),A1,B1), 0.f);
                a1v.y = fmaxf(fmaf(bf2f(H1.y),A1,B1), 0.f);
                a1v.z = fmaxf(fmaf(bf2f(H1.z),A1,B1), 0.f);
                a1v.w = fmaxf(fmaf(bf2f(H1.w),A1,B1), 0.f);
            } else {
                a0  = *(const float4*)(src0 + base);
                a1v = *(const float4*)(src0 + base + 1024);
                if (mode == 1) {
                    float f0 = kbf[ch0], f1 = kbf[ch1];
                    a0.x += f0; a0.y += f0; a0.z += f0; a0.w += f0;
                    a1v.x += f1; a1v.y += f1; a1v.z += f1; a1v.w += f1;
                    const u16* kps[5] = {kp0, kp1, kp2, kp3, kp4};
#pragma unroll
                    for (int jj = 0; jj < 5; ++jj) {
                        if (jj >= nk) break;
                        ushort4 kv0 = *(const ushort4*)(kps[jj] + base);
                        ushort4 kv1 = *(const ushort4*)(kps[jj] + base + 1024);
                        float fa0 = kaf[jj][ch0], fa1 = kaf[jj][ch1];
                        a0.x = fmaf(fa0, bf2f(kv0.x), a0.x);
                        a0.y = fmaf(fa0, bf2f(kv0.y), a0.y);
                        a0.z = fmaf(fa0, bf2f(kv0.z), a0.z);
                        a0.w = fmaf(fa0, bf2f(kv0.w), a0.w);
                        a1v.x = fmaf(fa1, bf2f(kv1.x), a1v.x);
                        a1v.y = fmaf(fa1, bf2f(kv1.y), a1v.y);
                        a1v.z = fmaf(fa1, bf2f(kv1.z), a1v.z);
                        a1v.w = fmaf(fa1, bf2f(kv1.w), a1v.w);
                    }
                }
            }
        }
        float v0[4] = {a0.x, a0.y, a0.z, a0.w};
        float v1[4] = {a1v.x, a1v.y, a1v.z, a1v.w};
        int c8 = c2 >> 2, cl = c2 & 3;
        int pbase = rr*34 + 1 + q4*4;
#pragma unroll
        for (int j = 0; j < 4; ++j) {
            int p = pbase + j;
            int au = p*64 + swz8(c8, p)*8 + cl*2;
            u16 h0,l0,h1,l1;
            split2(v0[j], h0, l0);
            split2(v1[j], h1, l1);
            *(unsigned*)&lds_in[au]         = (unsigned)h0 | ((unsigned)h1 << 16);
            *(unsigned*)&lds_in[au + PLANE] = (unsigned)l0 | ((unsigned)l1 << 16);
        }
    }
    // zero horizontal halo cols (col 0 and 33): 4 rows x 2 cols x 2 planes
#pragma unroll
    for (int i = 0; i < 2; ++i) {
        int u = tid + i*256;           // 0..511
        int c2 = u & 31;
        int t3 = u >> 5;               // 0..15
        int rr = t3 & 3;
        int e  = (t3 >> 2) & 1;
        int pl = t3 >> 3;
        int p  = rr*34 + e*33;
        int au = p*64 + swz8(c2 >> 2, p)*8 + (c2 & 3)*2 + pl*PLANE;
        *(unsigned*)&lds_in[au] = 0u;
    }
    __syncthreads();

    // ---- MFMA loop ----
    f32x4 acc[2][2] = {};
    for (int tap = 0; tap < 9; ++tap) {
        const int dy = tap / 3;
        const int dx = tap - dy*3;
        const int rowoff = (r0 + dy)*34 + dx;
        const u16* wtap = wt + (size_t)tap*8192;
#pragma unroll
        for (int kc = 0; kc < 2; ++kc) {
            bf16x8 A[2][2], Bf[2][2];
#pragma unroll
            for (int mt = 0; mt < 2; ++mt)
#pragma unroll
                for (int ty = 0; ty < 2; ++ty)
                    A[mt][ty] = *(const bf16x8*)
                        &wtap[(((kc*4 + mh*2 + mt)*2+ty)*64 + lane)*8];
#pragma unroll
            for (int nt = 0; nt < 2; ++nt) {
                int p = rowoff + nt*16 + n15;
                int au = p*64 + swz8(kc*4 + quad, p)*8;
                Bf[nt][0] = *(const bf16x8*)&lds_in[au];
                Bf[nt][1] = *(const bf16x8*)&lds_in[au + PLANE];
            }
#pragma unroll
            for (int mt = 0; mt < 2; ++mt)
#pragma unroll
                for (int nt = 0; nt < 2; ++nt) {
                    acc[mt][nt] = __builtin_amdgcn_mfma_f32_16x16x32_bf16(
                        A[mt][0], Bf[nt][0], acc[mt][nt], 0, 0, 0);
                    acc[mt][nt] = __builtin_amdgcn_mfma_f32_16x16x32_bf16(
                        A[mt][0], Bf[nt][1], acc[mt][nt], 0, 0, 0);
                    acc[mt][nt] = __builtin_amdgcn_mfma_f32_16x16x32_bf16(
                        A[mt][1], Bf[nt][0], acc[mt][nt], 0, 0, 0);
                }
        }
    }

    // ---- epilogue: write bf16 out + per-block GN partials ----
    const int orow = rt*2 + r0;
#pragma unroll
    for (int mt = 0; mt < 2; ++mt) {
#pragma unroll
        for (int r = 0; r < 4; ++r) {
            int cout = mh*32 + mt*16 + quad*4 + r;
            float bs = bias[cout];
            const float* sp = smap + (size_t)cout*1024 + orow*32;
            u16* op = out + (((size_t)b*64 + cout)*32 + orow)*32;
            float v0 = acc[mt][0][r] + bs + tval*sp[n15];
            float v1 = acc[mt][1][r] + bs + tval*sp[16 + n15];
            op[n15]      = bf16_rn(v0);
            op[16 + n15] = bf16_rn(v1);
            float s = v0 + v1;
            float q = v0*v0 + v1*v1;
            s += __shfl_xor(s, 1); q += __shfl_xor(q, 1);
            s += __shfl_xor(s, 2); q += __shfl_xor(q, 2);
            s += __shfl_xor(s, 4); q += __shfl_xor(q, 4);
            s += __shfl_xor(s, 8); q += __shfl_xor(q, 8);
            if (n15 == 0) { ps[r0*64 + cout] = s; pss[r0*64 + cout] = q; }
        }
    }
    __syncthreads();
    if (tid < 32) {
        int g = tid;
        float S  = (ps[2*g]  + ps[2*g+1])  + (ps[64+2*g]  + ps[64+2*g+1]);
        float SS = (pss[2*g] + pss[2*g+1]) + (pss[64+2*g] + pss[64+2*g+1]);
        float* pp = part + ((((size_t)slot_out*64 + b)*32 + g)*NRT + rt)*2;
        pp[0] = S; pp[1] = SS;
    }
}

// ---------------------------------------------------------------------------
// Per-step final combine (in-place): y += sum_j (B_j*dt) * gn2affine(k_j).
// ---------------------------------------------------------------------------
__global__ __launch_bounds__(256) void final_combine_k(
    float* __restrict__ y,
    const u16* __restrict__ k0, const u16* __restrict__ k1,
    const u16* __restrict__ k2, const u16* __restrict__ k3,
    const u16* __restrict__ k4, const u16* __restrict__ k5,
    const float* __restrict__ part,
    const float* __restrict__ g2s, const float* __restrict__ g2b,
    float b0, float b1, float b2, float b3, float b4, float b5)
{
    const int bidx = blockIdx.x;
    const int b = bidx >> 6, ch = bidx & 63, g = ch >> 1;
    const int t = threadIdx.x;
    __shared__ float rs[6][2];
    if (t < 12) {
        int jj = t >> 1, st = t & 1;
        const float* pp = part + ((((size_t)(1+jj)*64 + b)*32 + g)*NRT)*2 + st;
        float v = 0.f;
#pragma unroll
        for (int q = 0; q < NRT; ++q) v += pp[2*q];
        rs[jj][st] = v;
    }
    __syncthreads();
    const float bb[6] = {b0, b1, b2, b3, b4, b5};
    float fa[6], fcs = 0.f;
#pragma unroll
    for (int jj = 0; jj < 6; ++jj) {
        float mu   = rs[jj][0] * (1.f/2048.f);
        float var  = rs[jj][1] * (1.f/2048.f) - mu*mu;
        float rstd = rsqrtf(var + 1e-5f);
        float a = g2s[ch]*rstd;
        float c = g2b[ch] - mu*a;
        fa[jj] = bb[jj]*a;
        fcs   += bb[jj]*c;
    }
    const size_t base = ((size_t)bidx*256 + t)*4;
    float4 r = *(const float4*)(y + base);
    r.x += fcs; r.y += fcs; r.z += fcs; r.w += fcs;
    const u16* kp[6] = {k0, k1, k2, k3, k4, k5};
#pragma unroll
    for (int jj = 0; jj < 6; ++jj) {
        ushort4 kv = *(const ushort4*)(kp[jj] + base);
        r.x = fmaf(fa[jj], bf2f(kv.x), r.x);
        r.y = fmaf(fa[jj], bf2f(kv.y), r.y);
        r.z = fmaf(fa[jj], bf2f(kv.z), r.z);
        r.w = fmaf(fa[jj], bf2f(kv.w), r.w);
    }
    *(float4*)(y + base) = r;
}

// ---------------------------------------------------------------------------

static const double A_[5][5] = {
    {0.161, 0, 0, 0, 0},
    {-0.008480655492356989, 0.335480655492357, 0, 0, 0},
    {2.8971530571054935, -6.359448489975075, 4.3622954328695815, 0, 0},
    {5.325864828439257, -11.748883564062828, 7.4955393428898365, -0.09249506636175525, 0},
    {5.86145544294642, -12.92096931784711, 8.159367898576159, -0.071584973281401, -0.028269050394068383},
};
static const double B_[6] = {
    0.09646076681806523, 0.01, 0.4798896504144996,
    1.379008574103742, -3.290069515436081, 2.324710524099774,
};
static const double C_[5] = {0.161, 0.327, 0.9, 0.9800255409045097, 1.0};

extern "C" void kernel_launch(void* const* d_in, const int* in_sizes, int n_in,
                              void* d_out, int out_size, void* d_ws, size_t ws_size,
                              hipStream_t stream)
{
    const float* x   = (const float*)d_in[0];
    const float* c1w = (const float*)d_in[1];
    const float* c1b = (const float*)d_in[2];
    const float* g1s = (const float*)d_in[3];
    const float* g1b = (const float*)d_in[4];
    const float* c2w = (const float*)d_in[5];
    const float* c2b = (const float*)d_in[6];
    const float* g2s = (const float*)d_in[7];
    const float* g2b = (const float*)d_in[8];

    float* y  = (float*)d_out;
    u16*   wsb = (u16*)d_ws;
    u16*   h  = wsb;
    u16*   k[6];
    for (int i = 0; i < 6; ++i) k[i] = wsb + (size_t)(1 + i) * NELEM;
    u16*   wt1   = wsb + (size_t)7*NELEM;
    u16*   wt2   = wt1 + 73728;
    float* smap1 = (float*)(wt2 + 73728);
    float* smap2 = smap1 + 65536;
    float* part  = smap2 + 65536;    // 7*64*32*16*2 floats

    const double dt = 0.125;
    const float dtf = 0.125f;

    prep_w_k<<<36, 256, 0, stream>>>(c1w, wt1);
    prep_w_k<<<36, 256, 0, stream>>>(c2w, wt2);
    smap_k<<<256, 256, 0, stream>>>(c1w, smap1);
    smap_k<<<256, 256, 0, stream>>>(c2w, smap2);

    hipMemcpyAsync(y, x, (size_t)NELEM * sizeof(float),
                   hipMemcpyDeviceToDevice, stream);

    const dim3 cgrid(NRT, BB);

    for (int s = 0; s < 8; ++s) {
        const float t0 = dtf * (float)s;
        for (int j = 0; j < 6; ++j) {
            const float tj = (j == 0) ? t0 : t0 + (float)C_[j-1] * dtf;
            float a[5] = {0,0,0,0,0};
            for (int i = 0; i < j; ++i) a[i] = (float)(A_[j-1][i] * dt);
            // conv1: stage combine on read (mode 1; raw mode 0 at j==0),
            // GN1 stats -> slot 0; out = h (bf16)
            conv_mfma_k<<<cgrid, 256, 0, stream>>>(
                y, nullptr, k[0], k[1], k[2], k[3], k[4],
                part, g1s, g1b, g2s, g2b,
                wt1, smap1, c1b, h, tj,
                (j == 0) ? 0 : 1, j, 0, 0,
                a[0], a[1], a[2], a[3], a[4]);
            // conv2: GN1 affine+ReLU on bf16 read (slot 0), GN2 stats -> 1+j
            conv_mfma_k<<<cgrid, 256, 0, stream>>>(
                nullptr, h, nullptr, nullptr, nullptr, nullptr, nullptr,
                part, g1s, g1b, g2s, g2b,
                wt2, smap2, c2b, k[j], tj,
                2, 0, 0, 1 + j,
                0.f, 0.f, 0.f, 0.f, 0.f);
        }
        final_combine_k<<<4096, 256, 0, stream>>>(
            y, k[0], k[1], k[2], k[3], k[4], k[5], part, g2s, g2b,
            (float)(B_[0]*dt), (float)(B_[1]*dt), (float)(B_[2]*dt),
            (float)(B_[3]*dt), (float)(B_[4]*dt), (float)(B_[5]*dt));
    }
}

// Round 10
// 2445.840 us; speedup vs baseline: 1.5133x; 1.1847x over previous
//
#include <hip/hip_runtime.h>

typedef __attribute__((ext_vector_type(8))) __bf16 bf16x8;
typedef __attribute__((ext_vector_type(4))) float f32x4;
typedef unsigned short u16;

#define BB 64
#define NPIX 1024
#define NELEM (BB*64*NPIX)           // 4194304
#define NRT 8                        // row-tiles of 4 rows

// LDS input layout: [plane hi/lo][pixel 6*34][chunk-slot swizzled 8x8 u16]
#define PLANE (6*34*64)              // 13056 u16 per plane

__device__ __forceinline__ int swz8(int c8, int p) {
    return (c8 + ((p + (p >> 2)) & 7)) & 7;
}

__device__ __forceinline__ u16 bf16_rn(float x) {
    unsigned u = __float_as_uint(x);
    unsigned r = u + 0x7FFFu + ((u >> 16) & 1u);
    return (u16)(r >> 16);
}
__device__ __forceinline__ float bf2f(u16 u) {
    return __uint_as_float(((unsigned)u) << 16);
}
__device__ __forceinline__ void split2(float x, u16& h, u16& l) {
    h = bf16_rn(x);
    float hf = __uint_as_float(((unsigned)h) << 16);
    l = bf16_rn(x - hf);
}

// ---------------------------------------------------------------------------
__global__ __launch_bounds__(256) void prep_w_k(
    const float* __restrict__ w, u16* __restrict__ wt)
{
    int t = blockIdx.x*256 + threadIdx.x;
    if (t >= 9216) return;
    int lane = t & 63;
    int f = t >> 6;
    int ty  = f & 1;
    int mt  = (f >> 1) & 3;
    int kc  = (f >> 3) & 1;
    int tap = f >> 4;
    int cout = mt*16 + (lane & 15);
    int quad = lane >> 4;
    u16 v[8];
#pragma unroll
    for (int j = 0; j < 8; ++j) {
        int cin = kc*32 + quad*8 + j;
        float x = w[((size_t)cout*65 + (cin+1))*9 + tap];
        u16 h, l; split2(x, h, l);
        v[j] = ty ? l : h;
    }
    u16* dst = wt + ((size_t)tap*8192 + (((kc*4+mt)*2+ty)*64 + lane)*8);
    *(ushort4*)(dst)     = make_ushort4(v[0], v[1], v[2], v[3]);
    *(ushort4*)(dst + 4) = make_ushort4(v[4], v[5], v[6], v[7]);
}

__global__ __launch_bounds__(256) void smap_k(
    const float* __restrict__ w, float* __restrict__ smap)
{
    int t = blockIdx.x*256 + threadIdx.x;
    int cout = t >> 10;
    int pix = t & 1023;
    int y = pix >> 5, x = pix & 31;
    float s = 0.f;
#pragma unroll
    for (int dy = 0; dy < 3; ++dy)
#pragma unroll
        for (int dx = 0; dx < 3; ++dx) {
            int yy = y + dy - 1, xx = x + dx - 1;
            if ((unsigned)yy < 32u && (unsigned)xx < 32u)
                s += w[(size_t)cout*65*9 + dy*3 + dx];
        }
    smap[t] = s;
}

// ---------------------------------------------------------------------------
// Fused conv3x3 (bf16 hi/lo MFMA). 4-row tiles, 512-thread blocks (8 waves),
// 2 blocks/CU = 16 waves/CU. Wave wv: row (wv&3), cout-half (wv>>2).
//  mode 0: v = src0 (fp32, raw)
//  mode 1: v = src0 + fc[ch] + sum_{jj<nk} fa[jj][ch]*bf2f(k_jj)
//  mode 2: v = relu(ka[ch]*bf2f(srcb) + kb[ch])
// ---------------------------------------------------------------------------
__global__ __launch_bounds__(512, 4) void conv_mfma_k(
    const float* __restrict__ src0, const u16* __restrict__ srcb,
    const u16* __restrict__ kp0, const u16* __restrict__ kp1,
    const u16* __restrict__ kp2, const u16* __restrict__ kp3,
    const u16* __restrict__ kp4,
    float* __restrict__ part,
    const float* __restrict__ gns, const float* __restrict__ gnb,
    const float* __restrict__ gks, const float* __restrict__ gkb,
    const u16* __restrict__ wt, const float* __restrict__ smap,
    const float* __restrict__ bias, u16* __restrict__ out, float tval,
    int mode, int nk, int slot_in, int slot_out,
    float a1, float a2, float a3, float a4, float a5)
{
    __shared__ u16 lds_in[2*PLANE];          // 52224 B
    __shared__ float kaf[5][64];
    __shared__ float kbf[64];
    __shared__ float sgA[5][64];
    __shared__ float ps[256], pss[256];      // [row4][cout64]
    __shared__ float rg[64], rgq[64];

    const int rt  = blockIdx.x;              // 0..7
    const int b   = blockIdx.y;
    const int tid = threadIdx.x;
    const int wv   = tid >> 6;               // 0..7
    const int lane = tid & 63;
    const int quad = lane >> 4;
    const int n15  = lane & 15;
    const int r0   = wv & 3;                 // row in tile
    const int mh   = wv >> 2;                // cout half

    // ---- prelude: per-channel affine coefficients ----
    if (mode == 2) {
        if (tid < 64) {
            int g = tid & 31, st = tid >> 5;
            const float* pp = part + ((((size_t)slot_in*64 + b)*32 + g)*NRT)*2 + st;
            float v = 0.f;
#pragma unroll
            for (int q = 0; q < NRT; ++q) v += pp[2*q];
            sgA[0][st*32+g] = v;
        }
        __syncthreads();
        if (tid < 64) {
            int g = tid >> 1;
            float mu   = sgA[0][g] * (1.f/2048.f);
            float var  = sgA[0][32+g] * (1.f/2048.f) - mu*mu;
            float rstd = rsqrtf(var + 1e-5f);
            float a = gns[tid]*rstd;
            kaf[0][tid] = a;
            kbf[tid] = gnb[tid] - mu*a;
        }
    } else if (mode == 1) {
        if (tid < 64) {
            int g = tid & 31, st = tid >> 5;
            for (int jj = 0; jj < nk; ++jj) {
                const float* pp = part + ((((size_t)(1+jj)*64 + b)*32 + g)*NRT)*2 + st;
                float v = 0.f;
#pragma unroll
                for (int q = 0; q < NRT; ++q) v += pp[2*q];
                sgA[jj][st*32+g] = v;
            }
        }
        __syncthreads();
        if (tid < 64) {
            const float aa[5] = {a1, a2, a3, a4, a5};
            int g = tid >> 1;
            float acb = 0.f;
            for (int jj = 0; jj < nk; ++jj) {
                float mu   = sgA[jj][g] * (1.f/2048.f);
                float var  = sgA[jj][32+g] * (1.f/2048.f) - mu*mu;
                float rstd = rsqrtf(var + 1e-5f);
                float a = gks[tid]*rstd;
                float c = gkb[tid] - mu*a;
                kaf[jj][tid] = aa[jj]*a;
                acb += aa[jj]*c;
            }
            kbf[tid] = acb;
        }
    } else {
        if (tid < 64) { kaf[0][tid] = 1.f; kbf[tid] = 0.f; }
    }
    __syncthreads();

    // ---- stage input: 32 ch-pairs x 6 rows x 8 col-quads (1536 units) ----
#pragma unroll
    for (int i = 0; i < 3; ++i) {
        int u  = tid + i*512;          // 0..1535
        int q4 = u & 7;
        int t2 = u >> 3;               // 0..191
        int rr = t2 % 6;
        int c2 = t2 / 6;               // 0..31
        int gr = rt*4 + rr - 1;
        bool ok = (unsigned)gr < 32u;
        int ch0 = c2*2, ch1 = ch0 + 1;
        float4 a0 = make_float4(0.f,0.f,0.f,0.f), a1v = a0;
        if (ok) {
            const size_t base = (((size_t)b*64 + ch0)*32 + gr)*32 + q4*4;
            if (mode == 2) {
                ushort4 H0 = *(const ushort4*)(srcb + base);
                ushort4 H1 = *(const ushort4*)(srcb + base + 1024);
                float A0 = kaf[0][ch0], B0 = kbf[ch0];
                float A1 = kaf[0][ch1], B1 = kbf[ch1];
                a0.x = fmaxf(fmaf(bf2f(H0.x),A0,B0), 0.f);
                a0.y = fmaxf(fmaf(bf2f(H0.y),A0,B0), 0.f);
                a0.z = fmaxf(fmaf(bf2f(H0.z),A0,B0), 0.f);
                a0.w = fmaxf(fmaf(bf2f(H0.w),A0,B0), 0.f);
                a1v.x = fmaxf(fmaf(bf2f(H1.x),A1,B1), 0.f);
                a1v.y = fmaxf(fmaf(bf2f(H1.y),A1,B1), 0.f);
                a1v.z = fmaxf(fmaf(bf2f(H1.z),A1,B1), 0.f);
                a1v.w = fmaxf(fmaf(bf2f(H1.w),A1,B1), 0.f);
            } else {
                a0  = *(const float4*)(src0 + base);
                a1v = *(const float4*)(src0 + base + 1024);
                if (mode == 1) {
                    float f0 = kbf[ch0], f1 = kbf[ch1];
                    a0.x += f0; a0.y += f0; a0.z += f0; a0.w += f0;
                    a1v.x += f1; a1v.y += f1; a1v.z += f1; a1v.w += f1;
                    const u16* kps[5] = {kp0, kp1, kp2, kp3, kp4};
#pragma unroll
                    for (int jj = 0; jj < 5; ++jj) {
                        if (jj >= nk) break;
                        ushort4 kv0 = *(const ushort4*)(kps[jj] + base);
                        ushort4 kv1 = *(const ushort4*)(kps[jj] + base + 1024);
                        float fa0 = kaf[jj][ch0], fa1 = kaf[jj][ch1];
                        a0.x = fmaf(fa0, bf2f(kv0.x), a0.x);
                        a0.y = fmaf(fa0, bf2f(kv0.y), a0.y);
                        a0.z = fmaf(fa0, bf2f(kv0.z), a0.z);
                        a0.w = fmaf(fa0, bf2f(kv0.w), a0.w);
                        a1v.x = fmaf(fa1, bf2f(kv1.x), a1v.x);
                        a1v.y = fmaf(fa1, bf2f(kv1.y), a1v.y);
                        a1v.z = fmaf(fa1, bf2f(kv1.z), a1v.z);
                        a1v.w = fmaf(fa1, bf2f(kv1.w), a1v.w);
                    }
                }
            }
        }
        float v0[4] = {a0.x, a0.y, a0.z, a0.w};
        float v1[4] = {a1v.x, a1v.y, a1v.z, a1v.w};
        int c8 = c2 >> 2, cl = c2 & 3;
        int pbase = rr*34 + 1 + q4*4;
#pragma unroll
        for (int j = 0; j < 4; ++j) {
            int p = pbase + j;
            int au = p*64 + swz8(c8, p)*8 + cl*2;
            u16 h0,l0,h1,l1;
            split2(v0[j], h0, l0);
            split2(v1[j], h1, l1);
            *(unsigned*)&lds_in[au]         = (unsigned)h0 | ((unsigned)h1 << 16);
            *(unsigned*)&lds_in[au + PLANE] = (unsigned)l0 | ((unsigned)l1 << 16);
        }
    }
    // zero horizontal halo cols (col 0 and 33): 6 rows x 2 cols x 32 c2 x 2 pl
#pragma unroll
    for (int i = 0; i < 2; ++i) {
        int u = tid + i*512;           // 0..1023, need <768
        if (u < 768) {
            int c2 = u & 31;
            int t3 = u >> 5;           // 0..23
            int rr = t3 % 6;
            int z  = t3 / 6;           // 0..3
            int e  = z & 1, pl = z >> 1;
            int p  = rr*34 + e*33;
            int au = p*64 + swz8(c2 >> 2, p)*8 + (c2 & 3)*2 + pl*PLANE;
            *(unsigned*)&lds_in[au] = 0u;
        }
    }
    __syncthreads();

    // ---- MFMA loop ----
    f32x4 acc[2][2] = {};
    for (int tap = 0; tap < 9; ++tap) {
        const int dy = tap / 3;
        const int dx = tap - dy*3;
        const int rowoff = (r0 + dy)*34 + dx;
        const u16* wtap = wt + (size_t)tap*8192;
#pragma unroll
        for (int kc = 0; kc < 2; ++kc) {
            bf16x8 A[2][2], Bf[2][2];
#pragma unroll
            for (int mt = 0; mt < 2; ++mt)
#pragma unroll
                for (int ty = 0; ty < 2; ++ty)
                    A[mt][ty] = *(const bf16x8*)
                        &wtap[(((kc*4 + mh*2 + mt)*2+ty)*64 + lane)*8];
#pragma unroll
            for (int nt = 0; nt < 2; ++nt) {
                int p = rowoff + nt*16 + n15;
                int au = p*64 + swz8(kc*4 + quad, p)*8;
                Bf[nt][0] = *(const bf16x8*)&lds_in[au];
                Bf[nt][1] = *(const bf16x8*)&lds_in[au + PLANE];
            }
#pragma unroll
            for (int mt = 0; mt < 2; ++mt)
#pragma unroll
                for (int nt = 0; nt < 2; ++nt) {
                    acc[mt][nt] = __builtin_amdgcn_mfma_f32_16x16x32_bf16(
                        A[mt][0], Bf[nt][0], acc[mt][nt], 0, 0, 0);
                    acc[mt][nt] = __builtin_amdgcn_mfma_f32_16x16x32_bf16(
                        A[mt][0], Bf[nt][1], acc[mt][nt], 0, 0, 0);
                    acc[mt][nt] = __builtin_amdgcn_mfma_f32_16x16x32_bf16(
                        A[mt][1], Bf[nt][0], acc[mt][nt], 0, 0, 0);
                }
        }
    }

    // ---- epilogue: write bf16 out + per-block GN partials ----
    const int orow = rt*4 + r0;
#pragma unroll
    for (int mt = 0; mt < 2; ++mt) {
#pragma unroll
        for (int r = 0; r < 4; ++r) {
            int cout = mh*32 + mt*16 + quad*4 + r;
            float bs = bias[cout];
            const float* sp = smap + (size_t)cout*1024 + orow*32;
            u16* op = out + (((size_t)b*64 + cout)*32 + orow)*32;
            float v0 = acc[mt][0][r] + bs + tval*sp[n15];
            float v1 = acc[mt][1][r] + bs + tval*sp[16 + n15];
            op[n15]      = bf16_rn(v0);
            op[16 + n15] = bf16_rn(v1);
            float s = v0 + v1;
            float q = v0*v0 + v1*v1;
            s += __shfl_xor(s, 1); q += __shfl_xor(q, 1);
            s += __shfl_xor(s, 2); q += __shfl_xor(q, 2);
            s += __shfl_xor(s, 4); q += __shfl_xor(q, 4);
            s += __shfl_xor(s, 8); q += __shfl_xor(q, 8);
            if (n15 == 0) { ps[r0*64 + cout] = s; pss[r0*64 + cout] = q; }
        }
    }
    __syncthreads();
    if (tid < 64) {
        rg[tid]  = ps[tid]  + ps[64+tid]  + ps[128+tid]  + ps[192+tid];
        rgq[tid] = pss[tid] + pss[64+tid] + pss[128+tid] + pss[192+tid];
    }
    __syncthreads();
    if (tid < 32) {
        float S  = rg[2*tid]  + rg[2*tid+1];
        float SS = rgq[2*tid] + rgq[2*tid+1];
        float* pp = part + ((((size_t)slot_out*64 + b)*32 + tid)*NRT + rt)*2;
        pp[0] = S; pp[1] = SS;
    }
}

// ---------------------------------------------------------------------------
// Per-step final combine (in-place): y += sum_j (B_j*dt) * gn2affine(k_j).
// ---------------------------------------------------------------------------
__global__ __launch_bounds__(256) void final_combine_k(
    float* __restrict__ y,
    const u16* __restrict__ k0, const u16* __restrict__ k1,
    const u16* __restrict__ k2, const u16* __restrict__ k3,
    const u16* __restrict__ k4, const u16* __restrict__ k5,
    const float* __restrict__ part,
    const float* __restrict__ g2s, const float* __restrict__ g2b,
    float b0, float b1, float b2, float b3, float b4, float b5)
{
    const int bidx = blockIdx.x;
    const int b = bidx >> 6, ch = bidx & 63, g = ch >> 1;
    const int t = threadIdx.x;
    __shared__ float rs[6][2];
    if (t < 12) {
        int jj = t >> 1, st = t & 1;
        const float* pp = part + ((((size_t)(1+jj)*64 + b)*32 + g)*NRT)*2 + st;
        float v = 0.f;
#pragma unroll
        for (int q = 0; q < NRT; ++q) v += pp[2*q];
        rs[jj][st] = v;
    }
    __syncthreads();
    const float bb[6] = {b0, b1, b2, b3, b4, b5};
    float fa[6], fcs = 0.f;
#pragma unroll
    for (int jj = 0; jj < 6; ++jj) {
        float mu   = rs[jj][0] * (1.f/2048.f);
        float var  = rs[jj][1] * (1.f/2048.f) - mu*mu;
        float rstd = rsqrtf(var + 1e-5f);
        float a = g2s[ch]*rstd;
        float c = g2b[ch] - mu*a;
        fa[jj] = bb[jj]*a;
        fcs   += bb[jj]*c;
    }
    const size_t base = ((size_t)bidx*256 + t)*4;
    float4 r = *(const float4*)(y + base);
    r.x += fcs; r.y += fcs; r.z += fcs; r.w += fcs;
    const u16* kp[6] = {k0, k1, k2, k3, k4, k5};
#pragma unroll
    for (int jj = 0; jj < 6; ++jj) {
        ushort4 kv = *(const ushort4*)(kp[jj] + base);
        r.x = fmaf(fa[jj], bf2f(kv.x), r.x);
        r.y = fmaf(fa[jj], bf2f(kv.y), r.y);
        r.z = fmaf(fa[jj], bf2f(kv.z), r.z);
        r.w = fmaf(fa[jj], bf2f(kv.w), r.w);
    }
    *(float4*)(y + base) = r;
}

// ---------------------------------------------------------------------------

static const double A_[5][5] = {
    {0.161, 0, 0, 0, 0},
    {-0.008480655492356989, 0.335480655492357, 0, 0, 0},
    {2.8971530571054935, -6.359448489975075, 4.3622954328695815, 0, 0},
    {5.325864828439257, -11.748883564062828, 7.4955393428898365, -0.09249506636175525, 0},
    {5.86145544294642, -12.92096931784711, 8.159367898576159, -0.071584973281401, -0.028269050394068383},
};
static const double B_[6] = {
    0.09646076681806523, 0.01, 0.4798896504144996,
    1.379008574103742, -3.290069515436081, 2.324710524099774,
};
static const double C_[5] = {0.161, 0.327, 0.9, 0.9800255409045097, 1.0};

extern "C" void kernel_launch(void* const* d_in, const int* in_sizes, int n_in,
                              void* d_out, int out_size, void* d_ws, size_t ws_size,
                              hipStream_t stream)
{
    const float* x   = (const float*)d_in[0];
    const float* c1w = (const float*)d_in[1];
    const float* c1b = (const float*)d_in[2];
    const float* g1s = (const float*)d_in[3];
    const float* g1b = (const float*)d_in[4];
    const float* c2w = (const float*)d_in[5];
    const float* c2b = (const float*)d_in[6];
    const float* g2s = (const float*)d_in[7];
    const float* g2b = (const float*)d_in[8];

    float* y  = (float*)d_out;
    u16*   wsb = (u16*)d_ws;
    u16*   h  = wsb;
    u16*   k[6];
    for (int i = 0; i < 6; ++i) k[i] = wsb + (size_t)(1 + i) * NELEM;
    u16*   wt1   = wsb + (size_t)7*NELEM;
    u16*   wt2   = wt1 + 73728;
    float* smap1 = (float*)(wt2 + 73728);
    float* smap2 = smap1 + 65536;
    float* part  = smap2 + 65536;    // 7*64*32*8*2 floats

    const double dt = 0.125;
    const float dtf = 0.125f;

    prep_w_k<<<36, 256, 0, stream>>>(c1w, wt1);
    prep_w_k<<<36, 256, 0, stream>>>(c2w, wt2);
    smap_k<<<256, 256, 0, stream>>>(c1w, smap1);
    smap_k<<<256, 256, 0, stream>>>(c2w, smap2);

    hipMemcpyAsync(y, x, (size_t)NELEM * sizeof(float),
                   hipMemcpyDeviceToDevice, stream);

    const dim3 cgrid(NRT, BB);

    for (int s = 0; s < 8; ++s) {
        const float t0 = dtf * (float)s;
        for (int j = 0; j < 6; ++j) {
            const float tj = (j == 0) ? t0 : t0 + (float)C_[j-1] * dtf;
            float a[5] = {0,0,0,0,0};
            for (int i = 0; i < j; ++i) a[i] = (float)(A_[j-1][i] * dt);
            // conv1: stage combine on read (mode 1; raw mode 0 at j==0),
            // GN1 stats -> slot 0; out = h (bf16)
            conv_mfma_k<<<cgrid, 512, 0, stream>>>(
                y, nullptr, k[0], k[1], k[2], k[3], k[4],
                part, g1s, g1b, g2s, g2b,
                wt1, smap1, c1b, h, tj,
                (j == 0) ? 0 : 1, j, 0, 0,
                a[0], a[1], a[2], a[3], a[4]);
            // conv2: GN1 affine+ReLU on bf16 read (slot 0), GN2 stats -> 1+j
            conv_mfma_k<<<cgrid, 512, 0, stream>>>(
                nullptr, h, nullptr, nullptr, nullptr, nullptr, nullptr,
                part, g1s, g1b, g2s, g2b,
                wt2, smap2, c2b, k[j], tj,
                2, 0, 0, 1 + j,
                0.f, 0.f, 0.f, 0.f, 0.f);
        }
        final_combine_k<<<4096, 256, 0, stream>>>(
            y, k[0], k[1], k[2], k[3], k[4], k[5], part, g2s, g2b,
            (float)(B_[0]*dt), (float)(B_[1]*dt), (float)(B_[2]*dt),
            (float)(B_[3]*dt), (float)(B_[4]*dt), (float)(B_[5]*dt));
    }
}